// Round 2
// baseline (483.241 us; speedup 1.0000x reference)
//
#include <hip/hip_runtime.h>
#include <hip/hip_bf16.h>
#include <cstddef>

#define NND 94
#define NPAD 96

typedef __attribute__((ext_vector_type(8))) short sh8;
typedef __attribute__((ext_vector_type(4))) float f4v;

__device__ __forceinline__ float ftanh(float x) {
    // tanh(x) = 1 - 2/(e^{2x}+1); saturates correctly for |x| large
    float e = __expf(2.0f * x);
    return 1.0f - 2.0f / (e + 1.0f);
}

// ---------------- K0 (merged): block 0 builds dense normalized A^T (96x96, zeroed);
// blocks 1.. pack Wfc into bf16 hi/lo in MFMA B-fragment order, COLUMN-INTERLEAVED:
// for 64-col group g, MFMA tile sub s (0..3), internal col j = lane&15:
//   global col n = g*64 + j*4 + s      (linear tile index ntile = g*4 + s)
// This makes the GEMM epilogue's 4 nt-accumulators hold 4 CONSECUTIVE output cols.
__global__ void k_prep(const int* __restrict__ ei, const float* __restrict__ ew,
                       float* __restrict__ At, int E,
                       const float* __restrict__ Wfc, __hip_bfloat16* __restrict__ wp_hi,
                       __hip_bfloat16* __restrict__ wp_lo, int NOUT) {
    if (blockIdx.x == 0) {
        __shared__ float deg[NPAD];
        __shared__ float dinv[NPAD];
        int tid = threadIdx.x;
        for (int i = tid; i < NPAD * NPAD; i += blockDim.x) At[i] = 0.0f;
        if (tid < NPAD) deg[tid] = 0.0f;
        __syncthreads();
        for (int e = tid; e < E; e += blockDim.x)
            atomicAdd(&deg[ei[E + e]], ew[e]);
        __syncthreads();
        if (tid < NND) {
            float d = deg[tid] + 1.0f;  // self-loop weight 1.0
            dinv[tid] = d > 0.0f ? rsqrtf(d) : 0.0f;
        }
        __syncthreads();
        for (int e = tid; e < E; e += blockDim.x) {
            int s = ei[e], d = ei[E + e];
            atomicAdd(&At[s * NPAD + d], dinv[s] * ew[e] * dinv[d]);
        }
        if (tid < NND)
            atomicAdd(&At[tid * NPAD + tid], dinv[tid] * dinv[tid]);
        return;
    }
    int t = (blockIdx.x - 1) * blockDim.x + threadIdx.x;
    int total = (NOUT / 16) * 3 * 64;
    if (t >= total) return;
    int lane = t & 63;
    int kb = (t >> 6) % 3;
    int ntile = t / 192;
    int n = (ntile >> 2) * 64 + (lane & 15) * 4 + (ntile & 3);  // column-interleaved
    int kbase = kb * 32 + ((lane >> 4) << 3);
    size_t obase = (size_t)t * 8;
#pragma unroll
    for (int j = 0; j < 8; ++j) {
        int k = kbase + j;
        float v = (k < NND) ? Wfc[(size_t)n * NND + k] : 0.0f;
        __hip_bfloat16 h = __float2bfloat16(v);
        float rem = v - __bfloat162float(h);
        wp_hi[obase + j] = h;
        wp_lo[obase + j] = __float2bfloat16(rem);
    }
}

// ---------------- K1: fused GCN (fp32) -> h2 packed in MFMA A-fragment order (bf16) ----------------
// block: 512 threads = 8 groups x 64 lanes; lane = batch within block's 64-batch tile,
// group g owns 12 node-rows. A^T rows read via wave-uniform scalar loads.
#define K1_THREADS 512
#define NR 12

__global__ void __launch_bounds__(K1_THREADS) k_gcn(
    const float* __restrict__ feat, const float* __restrict__ W1,
    const float* __restrict__ b1, const float* __restrict__ W2,
    const float* __restrict__ b2p, const float* __restrict__ At,
    __hip_bfloat16* __restrict__ h2p) {
    extern __shared__ float lds[];
    float* xs = lds;              // [282][64]  (idx = m*3+k)
    float* zs = lds + 282 * 64;   // [94][64]

    int tid = threadIdx.x;
    int lane = tid & 63;
    int g = __builtin_amdgcn_readfirstlane(tid >> 6);
    int b0 = blockIdx.x * 64;

    // preload tiny weights (uniform)
    float w1[3][6], bb1[6], w2[6];
#pragma unroll
    for (int k = 0; k < 3; ++k)
#pragma unroll
        for (int c = 0; c < 6; ++c) w1[k][c] = W1[k * 6 + c];
#pragma unroll
    for (int c = 0; c < 6; ++c) { bb1[c] = b1[c]; w2[c] = W2[c]; }
    float b2 = b2p[0];

    // stage x: xs[(m*3+k)*64 + b] = feat[b0+b][m][k]
    for (int i = tid; i < 282 * 64; i += K1_THREADS) {
        int bl = i & 63;
        int idx = i >> 6;
        xs[idx * 64 + bl] = feat[(size_t)(b0 + bl) * 282 + idx];
    }
    __syncthreads();

    int nb = g * NR;

    // phase 1: y[n][k] = sum_m At[m][n] * x[m][k]
    float y[NR][3];
#pragma unroll
    for (int i = 0; i < NR; ++i)
#pragma unroll
        for (int k = 0; k < 3; ++k) y[i][k] = 0.0f;

    for (int m = 0; m < NND; ++m) {
        float x0 = xs[(m * 3 + 0) * 64 + lane];
        float x1 = xs[(m * 3 + 1) * 64 + lane];
        float x2 = xs[(m * 3 + 2) * 64 + lane];
        const float* arow = At + m * NPAD + nb;
#pragma unroll
        for (int i = 0; i < NR; ++i) {
            float a = arow[i];
            y[i][0] += a * x0;
            y[i][1] += a * x1;
            y[i][2] += a * x2;
        }
    }

    // pointwise: z = tanh(y*W1 + b1) dot W2
#pragma unroll
    for (int i = 0; i < NR; ++i) {
        int n = nb + i;
        float z = 0.0f;
#pragma unroll
        for (int c = 0; c < 6; ++c) {
            float h = ftanh(y[i][0] * w1[0][c] + y[i][1] * w1[1][c] + y[i][2] * w1[2][c] + bb1[c]);
            z += h * w2[c];
        }
        if (n < NND) zs[n * 64 + lane] = z;
    }
    __syncthreads();

    // phase 2: s[n] = sum_m At[m][n] * z[m]
    float s[NR];
#pragma unroll
    for (int i = 0; i < NR; ++i) s[i] = 0.0f;
    for (int m = 0; m < NND; ++m) {
        float zv = zs[m * 64 + lane];
        const float* arow = At + m * NPAD + nb;
#pragma unroll
        for (int i = 0; i < NR; ++i) s[i] += arow[i] * zv;
    }

    // write h2 as bf16 in MFMA A-fragment order:
    // A-frag: lane' = (b&15) + 16*(k32>>3), element j = k32&7, tile = b>>4, kb = n>>5
    int b = b0 + lane;
    int tile = b >> 4;
    int mloc = b & 15;
#pragma unroll
    for (int i = 0; i < NR; ++i) {
        int n = nb + i;
        float h2 = (n < NND) ? ftanh(s[i] + b2) : 0.0f;
        int kb = n >> 5;
        int k32 = n & 31;
        int lp = mloc + ((k32 >> 3) << 4);
        size_t idx = ((size_t)(tile * 3 + kb) * 64 + lp) * 8 + (k32 & 7);
        h2p[idx] = __float2bfloat16(h2);
    }
}

// ---------------- K2: out[B,6400] = h2 @ Wfc^T + bfc, bf16 MFMA, Wfc hi+lo for accuracy ----------------
// block 256 = 4 waves; wave tile 64(M) x 64(N); K=96 in 3 k-blocks; no LDS.
// 1D grid with XCD-aware swizzle, partitioned by M: xcd = bid&7 owns a 2048-row slice,
// so per-XCD L2 working set = full wp (2.34 MB) + h2p slice (0.39 MB) < 4 MB.
// B packing is column-interleaved (see k_prep): acc[mt][nt][r] -> col nbase + (lane&15)*4 + nt.
// Epilogue: float4 NON-TEMPORAL stores (don't thrash L2 with the 419 MB output stream).
__global__ void __launch_bounds__(256) k_gemm(
    const __hip_bfloat16* __restrict__ h2p, const __hip_bfloat16* __restrict__ wp_hi,
    const __hip_bfloat16* __restrict__ wp_lo, const float* __restrict__ bfc,
    float* __restrict__ out, int NOUT) {
    int tid = threadIdx.x;
    int lane = tid & 63;
    int wid = tid >> 6;

    // XCD swizzle: nbn = NOUT/64 n-blocks, 64 m-blocks split 8 per XCD
    unsigned nbn = (unsigned)NOUT >> 6;          // 100
    unsigned bid = blockIdx.x;
    unsigned xcd = bid & 7;
    unsigned idx = bid >> 3;                     // 0 .. (nbn*8 - 1)
    unsigned msub = idx / nbn;                   // 0..7
    unsigned nb = idx - msub * nbn;              // 0..nbn-1
    unsigned mb = xcd * 8 + msub;                // 0..63

    int nbase = (int)nb * 64;
    int mbase = (int)mb * 256 + wid * 64;
    int mtile0 = mbase >> 4;
    int ntile0 = nbase >> 4;

    f4v acc[4][4];
#pragma unroll
    for (int mt = 0; mt < 4; ++mt)
#pragma unroll
        for (int nt = 0; nt < 4; ++nt) acc[mt][nt] = (f4v){0.0f, 0.0f, 0.0f, 0.0f};

#pragma unroll
    for (int kb = 0; kb < 3; ++kb) {
        sh8 af[4], bh[4], bl[4];
#pragma unroll
        for (int mt = 0; mt < 4; ++mt)
            af[mt] = *(const sh8*)(h2p + ((size_t)((mtile0 + mt) * 3 + kb) * 64 + lane) * 8);
#pragma unroll
        for (int nt = 0; nt < 4; ++nt) {
            size_t o = ((size_t)((ntile0 + nt) * 3 + kb) * 64 + lane) * 8;
            bh[nt] = *(const sh8*)(wp_hi + o);
            bl[nt] = *(const sh8*)(wp_lo + o);
        }
#pragma unroll
        for (int mt = 0; mt < 4; ++mt)
#pragma unroll
            for (int nt = 0; nt < 4; ++nt) {
                acc[mt][nt] = __builtin_amdgcn_mfma_f32_16x16x32_bf16(af[mt], bh[nt], acc[mt][nt], 0, 0, 0);
                acc[mt][nt] = __builtin_amdgcn_mfma_f32_16x16x32_bf16(af[mt], bl[nt], acc[mt][nt], 0, 0, 0);
            }
    }

    // epilogue: + bfc, float4 nt-store. C/D layout: MFMA col = lane&15, row = (lane>>4)*4 + r
    // column-interleaved packing => acc[mt][nt][r] is out col nbase + (lane&15)*4 + nt
    int colg = lane & 15;
    int rowq = (lane >> 4) * 4;
    int cbase = nbase + colg * 4;
    f4v bias = *(const f4v*)(bfc + cbase);

#pragma unroll
    for (int mt = 0; mt < 4; ++mt) {
#pragma unroll
        for (int r = 0; r < 4; ++r) {
            int row = mbase + mt * 16 + rowq + r;
            f4v v;
#pragma unroll
            for (int nt = 0; nt < 4; ++nt) v[nt] = acc[mt][nt][r] + bias[nt];
            __builtin_nontemporal_store(v, (f4v*)(out + (size_t)row * NOUT + cbase));
        }
    }
}

extern "C" void kernel_launch(void* const* d_in, const int* in_sizes, int n_in,
                              void* d_out, int out_size, void* d_ws, size_t ws_size,
                              hipStream_t stream) {
    const float* feat = (const float*)d_in[0];
    const int*   ei   = (const int*)d_in[1];
    const float* ew   = (const float*)d_in[2];
    const float* W1   = (const float*)d_in[3];
    const float* b1   = (const float*)d_in[4];
    const float* W2   = (const float*)d_in[5];
    const float* b2   = (const float*)d_in[6];
    const float* Wfc  = (const float*)d_in[7];
    const float* bfc  = (const float*)d_in[8];
    float* out = (float*)d_out;

    int E = in_sizes[1] / 2;         // 1504
    int B = in_sizes[0] / (NND * 3); // 16384
    int NOUT = in_sizes[8];          // 6400

    // workspace carve (16B-aligned offsets)
    char* ws = (char*)d_ws;
    float* At = (float*)ws;                                        // 96*96*4 = 36864 B
    __hip_bfloat16* h2p   = (__hip_bfloat16*)(ws + 40960);         // B*96*2   = 3145728 B
    __hip_bfloat16* wp_hi = (__hip_bfloat16*)(ws + 40960 + 3145728);           // 6400*96*2
    __hip_bfloat16* wp_lo = (__hip_bfloat16*)(ws + 40960 + 3145728 + 1228800); // 6400*96*2

    // merged adjacency-build + W packing: block 0 = adjacency, blocks 1.. = pack
    int packT = (NOUT / 16) * 3 * 64;
    int packBlocks = (packT + 255) / 256;
    k_prep<<<1 + packBlocks, 256, 0, stream>>>(ei, ew, At, E, Wfc, wp_hi, wp_lo, NOUT);

    size_t ldsz = (size_t)(282 * 64 + 94 * 64) * sizeof(float);  // 96256 B
    k_gcn<<<B / 64, K1_THREADS, ldsz, stream>>>(feat, W1, b1, W2, b2, At, h2p);

    // 1D grid, XCD-swizzled in-kernel: total = (NOUT/64) * (B/256) blocks
    int gemmBlocks = (NOUT / 64) * (B / 256);
    k_gemm<<<gemmBlocks, 256, 0, stream>>>(h2p, wp_hi, wp_lo, bfc, out, NOUT);
}

// Round 3
// 482.130 us; speedup vs baseline: 1.0023x; 1.0023x over previous
//
#include <hip/hip_runtime.h>
#include <hip/hip_bf16.h>
#include <cstddef>

#define NND 94
#define NPAD 96

typedef _Float16 f16x8 __attribute__((ext_vector_type(8)));
typedef __attribute__((ext_vector_type(4))) float f4v;

__device__ __forceinline__ float ftanh(float x) {
    // tanh(x) = 1 - 2/(e^{2x}+1); saturates correctly for |x| large
    float e = __expf(2.0f * x);
    return 1.0f - 2.0f / (e + 1.0f);
}

// ---------------- K0 (merged): block 0 builds dense normalized A^T (96x96, zeroed);
// blocks 1.. pack Wfc into fp16 in MFMA B-fragment order, COLUMN-INTERLEAVED:
// for 64-col group g, MFMA tile sub s (0..3), internal col j = lane&15:
//   global col n = g*64 + j*4 + s      (linear tile index ntile = g*4 + s)
// fp16 (10-bit mantissa) is accurate enough to skip the old bf16 hi/lo split:
// |W| <~ 0.5, |h2| <= 1 -> no range issues, per-product rel err ~2^-10.
__global__ void k_prep(const int* __restrict__ ei, const float* __restrict__ ew,
                       float* __restrict__ At, int E,
                       const float* __restrict__ Wfc, _Float16* __restrict__ wp,
                       int NOUT) {
    if (blockIdx.x == 0) {
        __shared__ float deg[NPAD];
        __shared__ float dinv[NPAD];
        int tid = threadIdx.x;
        for (int i = tid; i < NPAD * NPAD; i += blockDim.x) At[i] = 0.0f;
        if (tid < NPAD) deg[tid] = 0.0f;
        __syncthreads();
        for (int e = tid; e < E; e += blockDim.x)
            atomicAdd(&deg[ei[E + e]], ew[e]);
        __syncthreads();
        if (tid < NND) {
            float d = deg[tid] + 1.0f;  // self-loop weight 1.0
            dinv[tid] = d > 0.0f ? rsqrtf(d) : 0.0f;
        }
        __syncthreads();
        for (int e = tid; e < E; e += blockDim.x) {
            int s = ei[e], d = ei[E + e];
            atomicAdd(&At[s * NPAD + d], dinv[s] * ew[e] * dinv[d]);
        }
        if (tid < NND)
            atomicAdd(&At[tid * NPAD + tid], dinv[tid] * dinv[tid]);
        return;
    }
    int t = (blockIdx.x - 1) * blockDim.x + threadIdx.x;
    int total = (NOUT / 16) * 3 * 64;
    if (t >= total) return;
    int lane = t & 63;
    int kb = (t >> 6) % 3;
    int ntile = t / 192;
    int n = (ntile >> 2) * 64 + (lane & 15) * 4 + (ntile & 3);  // column-interleaved
    int kbase = kb * 32 + ((lane >> 4) << 3);
    size_t obase = (size_t)t * 8;
#pragma unroll
    for (int j = 0; j < 8; ++j) {
        int k = kbase + j;
        float v = (k < NND) ? Wfc[(size_t)n * NND + k] : 0.0f;
        wp[obase + j] = (_Float16)v;
    }
}

// ---------------- K1: fused GCN (fp32) -> h2 packed in MFMA A-fragment order (fp16) ----------------
// block: 512 threads = 8 groups x 64 lanes; lane = batch within block's 64-batch tile,
// group g owns 12 node-rows. A^T rows read via wave-uniform scalar loads.
#define K1_THREADS 512
#define NR 12

__global__ void __launch_bounds__(K1_THREADS) k_gcn(
    const float* __restrict__ feat, const float* __restrict__ W1,
    const float* __restrict__ b1, const float* __restrict__ W2,
    const float* __restrict__ b2p, const float* __restrict__ At,
    _Float16* __restrict__ h2p) {
    extern __shared__ float lds[];
    float* xs = lds;              // [282][64]  (idx = m*3+k)
    float* zs = lds + 282 * 64;   // [94][64]

    int tid = threadIdx.x;
    int lane = tid & 63;
    int g = __builtin_amdgcn_readfirstlane(tid >> 6);
    int b0 = blockIdx.x * 64;

    // preload tiny weights (uniform)
    float w1[3][6], bb1[6], w2[6];
#pragma unroll
    for (int k = 0; k < 3; ++k)
#pragma unroll
        for (int c = 0; c < 6; ++c) w1[k][c] = W1[k * 6 + c];
#pragma unroll
    for (int c = 0; c < 6; ++c) { bb1[c] = b1[c]; w2[c] = W2[c]; }
    float b2 = b2p[0];

    // stage x: xs[(m*3+k)*64 + b] = feat[b0+b][m][k]
    for (int i = tid; i < 282 * 64; i += K1_THREADS) {
        int bl = i & 63;
        int idx = i >> 6;
        xs[idx * 64 + bl] = feat[(size_t)(b0 + bl) * 282 + idx];
    }
    __syncthreads();

    int nb = g * NR;

    // phase 1: y[n][k] = sum_m At[m][n] * x[m][k]
    float y[NR][3];
#pragma unroll
    for (int i = 0; i < NR; ++i)
#pragma unroll
        for (int k = 0; k < 3; ++k) y[i][k] = 0.0f;

    for (int m = 0; m < NND; ++m) {
        float x0 = xs[(m * 3 + 0) * 64 + lane];
        float x1 = xs[(m * 3 + 1) * 64 + lane];
        float x2 = xs[(m * 3 + 2) * 64 + lane];
        const float* arow = At + m * NPAD + nb;
#pragma unroll
        for (int i = 0; i < NR; ++i) {
            float a = arow[i];
            y[i][0] += a * x0;
            y[i][1] += a * x1;
            y[i][2] += a * x2;
        }
    }

    // pointwise: z = tanh(y*W1 + b1) dot W2
#pragma unroll
    for (int i = 0; i < NR; ++i) {
        int n = nb + i;
        float z = 0.0f;
#pragma unroll
        for (int c = 0; c < 6; ++c) {
            float h = ftanh(y[i][0] * w1[0][c] + y[i][1] * w1[1][c] + y[i][2] * w1[2][c] + bb1[c]);
            z += h * w2[c];
        }
        if (n < NND) zs[n * 64 + lane] = z;
    }
    __syncthreads();

    // phase 2: s[n] = sum_m At[m][n] * z[m]
    float s[NR];
#pragma unroll
    for (int i = 0; i < NR; ++i) s[i] = 0.0f;
    for (int m = 0; m < NND; ++m) {
        float zv = zs[m * 64 + lane];
        const float* arow = At + m * NPAD + nb;
#pragma unroll
        for (int i = 0; i < NR; ++i) s[i] += arow[i] * zv;
    }

    // write h2 as fp16 in MFMA A-fragment order:
    // A-frag: lane' = (b&15) + 16*(k32>>3), element j = k32&7, tile = b>>4, kb = n>>5
    int b = b0 + lane;
    int tile = b >> 4;
    int mloc = b & 15;
#pragma unroll
    for (int i = 0; i < NR; ++i) {
        int n = nb + i;
        float h2 = (n < NND) ? ftanh(s[i] + b2) : 0.0f;
        int kb = n >> 5;
        int k32 = n & 31;
        int lp = mloc + ((k32 >> 3) << 4);
        size_t idx = ((size_t)(tile * 3 + kb) * 64 + lp) * 8 + (k32 & 7);
        h2p[idx] = (_Float16)h2;
    }
}

// ---------------- K2: out[B,6400] = h2 @ Wfc^T + bfc, fp16 MFMA (single pass) ----------------
// block 256 = 4 waves; wave tile 64(M) x 64(N); K=96 in 3 k-blocks; no LDS.
// 1D grid with XCD-aware swizzle by M (kept from r2: neutral but harmless).
// B packing is column-interleaved (see k_prep): acc[mt][nt][r] -> col nbase + (lane&15)*4 + nt.
// Epilogue: float4 NON-TEMPORAL stores (don't thrash L2 with the 419 MB output stream).
__global__ void __launch_bounds__(256) k_gemm(
    const _Float16* __restrict__ h2p, const _Float16* __restrict__ wp,
    const float* __restrict__ bfc, float* __restrict__ out, int NOUT) {
    int tid = threadIdx.x;
    int lane = tid & 63;
    int wid = tid >> 6;

    // XCD swizzle: nbn = NOUT/64 n-blocks, 64 m-blocks split 8 per XCD
    unsigned nbn = (unsigned)NOUT >> 6;          // 100
    unsigned bid = blockIdx.x;
    unsigned xcd = bid & 7;
    unsigned idx = bid >> 3;                     // 0 .. (nbn*8 - 1)
    unsigned msub = idx / nbn;                   // 0..7
    unsigned nb = idx - msub * nbn;              // 0..nbn-1
    unsigned mb = xcd * 8 + msub;                // 0..63

    int nbase = (int)nb * 64;
    int mbase = (int)mb * 256 + wid * 64;
    int mtile0 = mbase >> 4;
    int ntile0 = nbase >> 4;

    f4v acc[4][4];
#pragma unroll
    for (int mt = 0; mt < 4; ++mt)
#pragma unroll
        for (int nt = 0; nt < 4; ++nt) acc[mt][nt] = (f4v){0.0f, 0.0f, 0.0f, 0.0f};

#pragma unroll
    for (int kb = 0; kb < 3; ++kb) {
        f16x8 af[4], bf[4];
#pragma unroll
        for (int mt = 0; mt < 4; ++mt)
            af[mt] = *(const f16x8*)(h2p + ((size_t)((mtile0 + mt) * 3 + kb) * 64 + lane) * 8);
#pragma unroll
        for (int nt = 0; nt < 4; ++nt)
            bf[nt] = *(const f16x8*)(wp + ((size_t)((ntile0 + nt) * 3 + kb) * 64 + lane) * 8);
#pragma unroll
        for (int mt = 0; mt < 4; ++mt)
#pragma unroll
            for (int nt = 0; nt < 4; ++nt)
                acc[mt][nt] = __builtin_amdgcn_mfma_f32_16x16x32_f16(af[mt], bf[nt], acc[mt][nt], 0, 0, 0);
    }

    // epilogue: + bfc, float4 nt-store. C/D layout: MFMA col = lane&15, row = (lane>>4)*4 + r
    // column-interleaved packing => acc[mt][nt][r] is out col nbase + (lane&15)*4 + nt
    int colg = lane & 15;
    int rowq = (lane >> 4) * 4;
    int cbase = nbase + colg * 4;
    f4v bias = *(const f4v*)(bfc + cbase);

#pragma unroll
    for (int mt = 0; mt < 4; ++mt) {
#pragma unroll
        for (int r = 0; r < 4; ++r) {
            int row = mbase + mt * 16 + rowq + r;
            f4v v;
#pragma unroll
            for (int nt = 0; nt < 4; ++nt) v[nt] = acc[mt][nt][r] + bias[nt];
            __builtin_nontemporal_store(v, (f4v*)(out + (size_t)row * NOUT + cbase));
        }
    }
}

extern "C" void kernel_launch(void* const* d_in, const int* in_sizes, int n_in,
                              void* d_out, int out_size, void* d_ws, size_t ws_size,
                              hipStream_t stream) {
    const float* feat = (const float*)d_in[0];
    const int*   ei   = (const int*)d_in[1];
    const float* ew   = (const float*)d_in[2];
    const float* W1   = (const float*)d_in[3];
    const float* b1   = (const float*)d_in[4];
    const float* W2   = (const float*)d_in[5];
    const float* b2   = (const float*)d_in[6];
    const float* Wfc  = (const float*)d_in[7];
    const float* bfc  = (const float*)d_in[8];
    float* out = (float*)d_out;

    int E = in_sizes[1] / 2;         // 1504
    int B = in_sizes[0] / (NND * 3); // 16384
    int NOUT = in_sizes[8];          // 6400

    // workspace carve (16B-aligned offsets)
    char* ws = (char*)d_ws;
    float* At = (float*)ws;                                // 96*96*4 = 36864 B
    _Float16* h2p = (_Float16*)(ws + 40960);               // B*96*2   = 3145728 B
    _Float16* wp  = (_Float16*)(ws + 40960 + 3145728);     // 6400*96*2 = 1228800 B

    // merged adjacency-build + W packing: block 0 = adjacency, blocks 1.. = pack
    int packT = (NOUT / 16) * 3 * 64;
    int packBlocks = (packT + 255) / 256;
    k_prep<<<1 + packBlocks, 256, 0, stream>>>(ei, ew, At, E, Wfc, wp, NOUT);

    size_t ldsz = (size_t)(282 * 64 + 94 * 64) * sizeof(float);  // 96256 B
    k_gcn<<<B / 64, K1_THREADS, ldsz, stream>>>(feat, W1, b1, W2, b2, At, h2p);

    // 1D grid, XCD-swizzled in-kernel: total = (NOUT/64) * (B/256) blocks
    int gemmBlocks = (NOUT / 64) * (B / 256);
    k_gemm<<<gemmBlocks, 256, 0, stream>>>(h2p, wp, bfc, out, NOUT);
}

// Round 4
// 479.457 us; speedup vs baseline: 1.0079x; 1.0056x over previous
//
#include <hip/hip_runtime.h>
#include <hip/hip_bf16.h>
#include <cstddef>

#define NND 94
#define NPAD 96

typedef _Float16 f16x8 __attribute__((ext_vector_type(8)));
typedef __attribute__((ext_vector_type(4))) float f4v;

__device__ __forceinline__ float ftanh(float x) {
    // tanh(x) = 1 - 2/(e^{2x}+1); saturates correctly for |x| large
    float e = __expf(2.0f * x);
    return 1.0f - 2.0f / (e + 1.0f);
}

// ---------------- K0 (merged): block 0 builds dense normalized A^T (96x96, zeroed);
// blocks 1.. pack Wfc into fp16 in MFMA B-fragment order, COLUMN-INTERLEAVED:
// for 64-col group g, MFMA tile sub s (0..3), internal col j = lane&15:
//   global col n = g*64 + j*4 + s      (linear tile index ntile = g*4 + s)
// fp16 (10-bit mantissa): |W| <~ 0.5, |h2| <= 1 -> no range issues.
__global__ void k_prep(const int* __restrict__ ei, const float* __restrict__ ew,
                       float* __restrict__ At, int E,
                       const float* __restrict__ Wfc, _Float16* __restrict__ wp,
                       int NOUT) {
    if (blockIdx.x == 0) {
        __shared__ float deg[NPAD];
        __shared__ float dinv[NPAD];
        int tid = threadIdx.x;
        for (int i = tid; i < NPAD * NPAD; i += blockDim.x) At[i] = 0.0f;
        if (tid < NPAD) deg[tid] = 0.0f;
        __syncthreads();
        for (int e = tid; e < E; e += blockDim.x)
            atomicAdd(&deg[ei[E + e]], ew[e]);
        __syncthreads();
        if (tid < NND) {
            float d = deg[tid] + 1.0f;  // self-loop weight 1.0
            dinv[tid] = d > 0.0f ? rsqrtf(d) : 0.0f;
        }
        __syncthreads();
        for (int e = tid; e < E; e += blockDim.x) {
            int s = ei[e], d = ei[E + e];
            atomicAdd(&At[s * NPAD + d], dinv[s] * ew[e] * dinv[d]);
        }
        if (tid < NND)
            atomicAdd(&At[tid * NPAD + tid], dinv[tid] * dinv[tid]);
        return;
    }
    int t = (blockIdx.x - 1) * blockDim.x + threadIdx.x;
    int total = (NOUT / 16) * 3 * 64;
    if (t >= total) return;
    int lane = t & 63;
    int kb = (t >> 6) % 3;
    int ntile = t / 192;
    int n = (ntile >> 2) * 64 + (lane & 15) * 4 + (ntile & 3);  // column-interleaved
    int kbase = kb * 32 + ((lane >> 4) << 3);
    size_t obase = (size_t)t * 8;
#pragma unroll
    for (int j = 0; j < 8; ++j) {
        int k = kbase + j;
        float v = (k < NND) ? Wfc[(size_t)n * NND + k] : 0.0f;
        wp[obase + j] = (_Float16)v;
    }
}

// ---------------- K1: fused GCN (fp32) -> h2 packed in MFMA A-fragment order (fp16) ----------------
// block: 512 threads = 8 groups x 64 lanes; lane = batch within block's 64-batch tile,
// group g owns 12 node-rows. A^T rows read via wave-uniform scalar loads.
// Staging: GLOBAL side fully linear/coalesced (thread i reads feat[b0*282+i]);
// LDS xs row stride padded to 65 so the transposed write (idx fastest) is bank-conflict-free
// (bank advances by 65 mod 32 = 1 per lane) and phase-1 lane-linear reads stay conflict-free.
#define K1_THREADS 512
#define NR 12
#define XST 65  // padded LDS stride for xs

__global__ void __launch_bounds__(K1_THREADS) k_gcn(
    const float* __restrict__ feat, const float* __restrict__ W1,
    const float* __restrict__ b1, const float* __restrict__ W2,
    const float* __restrict__ b2p, const float* __restrict__ At,
    _Float16* __restrict__ h2p) {
    extern __shared__ float lds[];
    float* xs = lds;                 // [282][XST]  (idx = m*3+k, inner = batch-lane)
    float* zs = lds + 282 * XST;     // [94][64]

    int tid = threadIdx.x;
    int lane = tid & 63;
    int g = __builtin_amdgcn_readfirstlane(tid >> 6);
    int b0 = blockIdx.x * 64;

    // preload tiny weights (uniform)
    float w1[3][6], bb1[6], w2[6];
#pragma unroll
    for (int k = 0; k < 3; ++k)
#pragma unroll
        for (int c = 0; c < 6; ++c) w1[k][c] = W1[k * 6 + c];
#pragma unroll
    for (int c = 0; c < 6; ++c) { bb1[c] = b1[c]; w2[c] = W2[c]; }
    float b2 = b2p[0];

    // stage x: coalesced global read, transposed LDS write.
    // element i = bl*282 + idx  ->  xs[idx*XST + bl] = feat[b0*282 + i]
    {
        const float* gsrc = feat + (size_t)b0 * 282;
        for (int i = tid; i < 282 * 64; i += K1_THREADS) {
            int bl = i / 282;
            int idx = i - bl * 282;
            xs[idx * XST + bl] = gsrc[i];
        }
    }
    __syncthreads();

    int nb = g * NR;

    // phase 1: y[n][k] = sum_m At[m][n] * x[m][k]
    float y[NR][3];
#pragma unroll
    for (int i = 0; i < NR; ++i)
#pragma unroll
        for (int k = 0; k < 3; ++k) y[i][k] = 0.0f;

    for (int m = 0; m < NND; ++m) {
        float x0 = xs[(m * 3 + 0) * XST + lane];
        float x1 = xs[(m * 3 + 1) * XST + lane];
        float x2 = xs[(m * 3 + 2) * XST + lane];
        const float* arow = At + m * NPAD + nb;
#pragma unroll
        for (int i = 0; i < NR; ++i) {
            float a = arow[i];
            y[i][0] += a * x0;
            y[i][1] += a * x1;
            y[i][2] += a * x2;
        }
    }

    // pointwise: z = tanh(y*W1 + b1) dot W2
#pragma unroll
    for (int i = 0; i < NR; ++i) {
        int n = nb + i;
        float z = 0.0f;
#pragma unroll
        for (int c = 0; c < 6; ++c) {
            float h = ftanh(y[i][0] * w1[0][c] + y[i][1] * w1[1][c] + y[i][2] * w1[2][c] + bb1[c]);
            z += h * w2[c];
        }
        if (n < NND) zs[n * 64 + lane] = z;
    }
    __syncthreads();

    // phase 2: s[n] = sum_m At[m][n] * z[m]
    float s[NR];
#pragma unroll
    for (int i = 0; i < NR; ++i) s[i] = 0.0f;
    for (int m = 0; m < NND; ++m) {
        float zv = zs[m * 64 + lane];
        const float* arow = At + m * NPAD + nb;
#pragma unroll
        for (int i = 0; i < NR; ++i) s[i] += arow[i] * zv;
    }

    // write h2 as fp16 in MFMA A-fragment order:
    // A-frag: lane' = (b&15) + 16*(k32>>3), element j = k32&7, tile = b>>4, kb = n>>5
    int b = b0 + lane;
    int tile = b >> 4;
    int mloc = b & 15;
#pragma unroll
    for (int i = 0; i < NR; ++i) {
        int n = nb + i;
        float h2 = (n < NND) ? ftanh(s[i] + b2) : 0.0f;
        int kb = n >> 5;
        int k32 = n & 31;
        int lp = mloc + ((k32 >> 3) << 4);
        size_t idx = ((size_t)(tile * 3 + kb) * 64 + lp) * 8 + (k32 & 7);
        h2p[idx] = (_Float16)h2;
    }
}

// ---------------- K2: out[B,6400] = h2 @ Wfc^T + bfc, fp16 MFMA (single pass) ----------------
// block 256 = 4 waves; wave tile 64(M) x 64(N); K=96 in 3 k-blocks; no LDS.
// 1D grid with XCD-aware swizzle by M (neutral but harmless).
// B packing is column-interleaved (see k_prep): acc[mt][nt][r] -> col nbase + (lane&15)*4 + nt.
// Epilogue: float4 NON-TEMPORAL stores (write-stream is this kernel's floor: 419 MB fp32).
__global__ void __launch_bounds__(256) k_gemm(
    const _Float16* __restrict__ h2p, const _Float16* __restrict__ wp,
    const float* __restrict__ bfc, float* __restrict__ out, int NOUT) {
    int tid = threadIdx.x;
    int lane = tid & 63;
    int wid = tid >> 6;

    // XCD swizzle: nbn = NOUT/64 n-blocks, 64 m-blocks split 8 per XCD
    unsigned nbn = (unsigned)NOUT >> 6;          // 100
    unsigned bid = blockIdx.x;
    unsigned xcd = bid & 7;
    unsigned idx = bid >> 3;                     // 0 .. (nbn*8 - 1)
    unsigned msub = idx / nbn;                   // 0..7
    unsigned nb = idx - msub * nbn;              // 0..nbn-1
    unsigned mb = xcd * 8 + msub;                // 0..63

    int nbase = (int)nb * 64;
    int mbase = (int)mb * 256 + wid * 64;
    int mtile0 = mbase >> 4;
    int ntile0 = nbase >> 4;

    f4v acc[4][4];
#pragma unroll
    for (int mt = 0; mt < 4; ++mt)
#pragma unroll
        for (int nt = 0; nt < 4; ++nt) acc[mt][nt] = (f4v){0.0f, 0.0f, 0.0f, 0.0f};

#pragma unroll
    for (int kb = 0; kb < 3; ++kb) {
        f16x8 af[4], bf[4];
#pragma unroll
        for (int mt = 0; mt < 4; ++mt)
            af[mt] = *(const f16x8*)(h2p + ((size_t)((mtile0 + mt) * 3 + kb) * 64 + lane) * 8);
#pragma unroll
        for (int nt = 0; nt < 4; ++nt)
            bf[nt] = *(const f16x8*)(wp + ((size_t)((ntile0 + nt) * 3 + kb) * 64 + lane) * 8);
#pragma unroll
        for (int mt = 0; mt < 4; ++mt)
#pragma unroll
            for (int nt = 0; nt < 4; ++nt)
                acc[mt][nt] = __builtin_amdgcn_mfma_f32_16x16x32_f16(af[mt], bf[nt], acc[mt][nt], 0, 0, 0);
    }

    // epilogue: + bfc, float4 nt-store. C/D layout: MFMA col = lane&15, row = (lane>>4)*4 + r
    // column-interleaved packing => acc[mt][nt][r] is out col nbase + (lane&15)*4 + nt
    int colg = lane & 15;
    int rowq = (lane >> 4) * 4;
    int cbase = nbase + colg * 4;
    f4v bias = *(const f4v*)(bfc + cbase);

#pragma unroll
    for (int mt = 0; mt < 4; ++mt) {
#pragma unroll
        for (int r = 0; r < 4; ++r) {
            int row = mbase + mt * 16 + rowq + r;
            f4v v;
#pragma unroll
            for (int nt = 0; nt < 4; ++nt) v[nt] = acc[mt][nt][r] + bias[nt];
            __builtin_nontemporal_store(v, (f4v*)(out + (size_t)row * NOUT + cbase));
        }
    }
}

extern "C" void kernel_launch(void* const* d_in, const int* in_sizes, int n_in,
                              void* d_out, int out_size, void* d_ws, size_t ws_size,
                              hipStream_t stream) {
    const float* feat = (const float*)d_in[0];
    const int*   ei   = (const int*)d_in[1];
    const float* ew   = (const float*)d_in[2];
    const float* W1   = (const float*)d_in[3];
    const float* b1   = (const float*)d_in[4];
    const float* W2   = (const float*)d_in[5];
    const float* b2   = (const float*)d_in[6];
    const float* Wfc  = (const float*)d_in[7];
    const float* bfc  = (const float*)d_in[8];
    float* out = (float*)d_out;

    int E = in_sizes[1] / 2;         // 1504
    int B = in_sizes[0] / (NND * 3); // 16384
    int NOUT = in_sizes[8];          // 6400

    // workspace carve (16B-aligned offsets)
    char* ws = (char*)d_ws;
    float* At = (float*)ws;                                // 96*96*4 = 36864 B
    _Float16* h2p = (_Float16*)(ws + 40960);               // B*96*2   = 3145728 B
    _Float16* wp  = (_Float16*)(ws + 40960 + 3145728);     // 6400*96*2 = 1228800 B

    // merged adjacency-build + W packing: block 0 = adjacency, blocks 1.. = pack
    int packT = (NOUT / 16) * 3 * 64;
    int packBlocks = (packT + 255) / 256;
    k_prep<<<1 + packBlocks, 256, 0, stream>>>(ei, ew, At, E, Wfc, wp, NOUT);

    size_t ldsz = (size_t)(282 * XST + 94 * 64) * sizeof(float);  // 97384 B
    k_gcn<<<B / 64, K1_THREADS, ldsz, stream>>>(feat, W1, b1, W2, b2, At, h2p);

    // 1D grid, XCD-swizzled in-kernel: total = (NOUT/64) * (B/256) blocks
    int gemmBlocks = (NOUT / 64) * (B / 256);
    k_gemm<<<gemmBlocks, 256, 0, stream>>>(h2p, wp, bfc, out, NOUT);
}